// Round 1
// baseline (1040.527 us; speedup 1.0000x reference)
//
#include <hip/hip_runtime.h>
#include <hip/hip_bf16.h>

#define N_USERC 50000
#define N_ITEMC 100000
#define NNODE   150000
#define DIM     64
#define NLAYERS 3
#define NNZC    2400000
#define BATCH   1024

// ---------------------------------------------------------------------------
// helpers
// ---------------------------------------------------------------------------
__device__ __forceinline__ int block_excl_scan(int v, int* lds) {
    int lane = threadIdx.x & 63;
    int wid  = threadIdx.x >> 6;
    int nw   = (blockDim.x + 63) >> 6;
    int inc = v;
#pragma unroll
    for (int o = 1; o < 64; o <<= 1) {
        int n = __shfl_up(inc, o, 64);
        if (lane >= o) inc += n;
    }
    if (lane == 63) lds[wid] = inc;
    __syncthreads();
    if (wid == 0) {
        int tv = (lane < nw) ? lds[lane] : 0;
#pragma unroll
        for (int o = 1; o < 16; o <<= 1) {
            int n = __shfl_up(tv, o, 64);
            if (lane >= o) tv += n;
        }
        if (lane < nw) lds[lane] = tv;
    }
    __syncthreads();
    int woff = (wid == 0) ? 0 : lds[wid - 1];
    return woff + (inc - v);
}

// ---------------------------------------------------------------------------
// E construction
// ---------------------------------------------------------------------------
__global__ void k_copy_E(const float* __restrict__ ue, const float* __restrict__ ie,
                         float* __restrict__ E) {
    int i = blockIdx.x * blockDim.x + threadIdx.x;        // float4 index
    const int userEnd = N_USERC * DIM / 4;
    const int total   = NNODE * DIM / 4;
    if (i < total) {
        float4 v;
        if (i < userEnd) v = ((const float4*)ue)[i];
        else             v = ((const float4*)ie)[i - userEnd];
        ((float4*)E)[i] = v;
    }
}

__global__ void k_winner(const int* __restrict__ user_idx, int* __restrict__ winner) {
    int b = blockIdx.x * blockDim.x + threadIdx.x;
    if (b < BATCH) atomicMax(&winner[user_idx[b]], b);
}

__global__ void k_mlp_update(const float* __restrict__ user_emb,
                             const float* __restrict__ user_feat,
                             const float* __restrict__ l1w, const float* __restrict__ l1b,
                             const float* __restrict__ l2w, const float* __restrict__ l2b,
                             const float* __restrict__ ratio_p,
                             const int* __restrict__ user_idx,
                             const int* __restrict__ winner,
                             float* __restrict__ E) {
    int b = blockIdx.x;        // grid = BATCH, block = 64
    int d = threadIdx.x;
    int u = user_idx[b];
    if (winner[u] != b) return;                  // last-occurrence-wins (numpy semantics)
    float ratio = ratio_p[0];
    float uf0 = user_feat[b * 4 + 0], uf1 = user_feat[b * 4 + 1];
    float uf2 = user_feat[b * 4 + 2], uf3 = user_feat[b * 4 + 3];
    float acc = l2b[d];
#pragma unroll
    for (int j = 0; j < 32; ++j) {
        float h = l1b[j] + uf0 * l1w[0 * 32 + j] + uf1 * l1w[1 * 32 + j]
                         + uf2 * l1w[2 * 32 + j] + uf3 * l1w[3 * 32 + j];
        acc += h * l2w[j * DIM + d];
    }
    E[u * DIM + d] = user_emb[u * DIM + d] * (1.f - ratio) + acc * ratio;
}

// ---------------------------------------------------------------------------
// CSR build: hist -> (S1 block sums, S2 scan sums, S3 tile scan) -> scatter
// ---------------------------------------------------------------------------
__global__ void k_hist(const int* __restrict__ rows, int* __restrict__ counts) {
    int i = blockIdx.x * blockDim.x + threadIdx.x;
    if (i < NNZC) atomicAdd(&counts[rows[i]], 1);
}

__global__ void k_s1(const int* __restrict__ counts, int* __restrict__ bsums) {
    __shared__ int lds[16];
    int i = blockIdx.x * 1024 + threadIdx.x;
    int v = (i < NNODE) ? counts[i] : 0;
#pragma unroll
    for (int m = 32; m; m >>= 1) v += __shfl_xor(v, m, 64);
    if ((threadIdx.x & 63) == 0) lds[threadIdx.x >> 6] = v;
    __syncthreads();
    if (threadIdx.x == 0) {
        int s = 0;
#pragma unroll
        for (int w = 0; w < 16; ++w) s += lds[w];
        bsums[blockIdx.x] = s;
    }
}

__global__ void k_s2(int* __restrict__ bsums, int nblocks) {
    __shared__ int lds[16];
    int t = threadIdx.x;                    // block 256
    int v = (t < nblocks) ? bsums[t] : 0;
    int excl = block_excl_scan(v, lds);
    if (t < nblocks) bsums[t] = excl;
}

__global__ void k_s3(const int* __restrict__ counts, const int* __restrict__ bsums,
                     int* __restrict__ rowptr, int* __restrict__ cursor) {
    __shared__ int lds[16];
    int i = blockIdx.x * 1024 + threadIdx.x;
    int v = (i < NNODE) ? counts[i] : 0;
    int excl = block_excl_scan(v, lds);
    int pref = bsums[blockIdx.x] + excl;
    if (i < NNODE) {
        rowptr[i] = pref;
        cursor[i] = pref;
    } else if (i == NNODE) {
        rowptr[NNODE] = pref;               // == NNZ
    }
}

__global__ void k_scatter(const int* __restrict__ rows, const int* __restrict__ colsi,
                          const float* __restrict__ valsi, int* __restrict__ cursor,
                          int* __restrict__ colso, float* __restrict__ valso) {
    int i = blockIdx.x * blockDim.x + threadIdx.x;
    if (i < NNZC) {
        int r = rows[i];
        int p = atomicAdd(&cursor[r], 1);
        colso[p] = colsi[i];
        valso[p] = valsi[i];
    }
}

// ---------------------------------------------------------------------------
// SpMM: one wave per row, lane = dim. col/val broadcast via shfl.
// ---------------------------------------------------------------------------
__global__ __launch_bounds__(256) void k_spmm(const int* __restrict__ rowptr,
                                              const int* __restrict__ cols,
                                              const float* __restrict__ vals,
                                              const float* __restrict__ E,
                                              float* __restrict__ L) {
    int wid  = threadIdx.x >> 6;
    int lane = threadIdx.x & 63;
    int row  = blockIdx.x * 4 + wid;
    if (row >= NNODE) return;
    int s = rowptr[row], e = rowptr[row + 1];
    float acc = 0.f;
    for (int base = s; base < e; base += 64) {
        int n = e - base; if (n > 64) n = 64;
        int   c = 0; float v = 0.f;
        if (base + lane < e) { c = cols[base + lane]; v = vals[base + lane]; }
        for (int i = 0; i < n; ++i) {
            int   ci = __shfl(c, i, 64);
            float vi = __shfl(v, i, 64);
            acc += vi * E[ci * DIM + lane];
        }
    }
    L[row * DIM + lane] = acc;
}

// ---------------------------------------------------------------------------
// Transform: E_new = leaky_relu([L+E, L*E] @ [W1;W2] + b1 + b2), in place.
// Block 256, 128 rows/block, thread = 4 rows x 8 cols. K-chunks of 16.
// LDS: W 32KB + bias + 2 tiles 128x17 = ~50KB.
// ---------------------------------------------------------------------------
__global__ __launch_bounds__(256) void k_transform(const float* __restrict__ L,
                                                   const float* __restrict__ Ein,
                                                   const float* __restrict__ w1k,
                                                   const float* __restrict__ b1k,
                                                   const float* __restrict__ w2k,
                                                   const float* __restrict__ b2k,
                                                   float* __restrict__ Eout) {
    __shared__ float Wl[128 * 64];          // rows 0..63 = W1, 64..127 = W2
    __shared__ float bias[64];
    __shared__ float Atile[128 * 17];
    __shared__ float Ctile[128 * 17];

    int t = threadIdx.x;
    // load weights (each 4096 floats = 1024 float4)
    for (int idx = t; idx < 1024; idx += 256) {
        ((float4*)Wl)[idx]          = ((const float4*)w1k)[idx];
        ((float4*)(Wl + 4096))[idx] = ((const float4*)w2k)[idx];
    }
    if (t < 64) bias[t] = b1k[t] + b2k[t];

    const int rowbase = blockIdx.x * 128;
    const int ct = t & 7;       // col group: cols ct*8 .. ct*8+7
    const int rg = t >> 3;      // row group: rows rg*4 .. rg*4+3

    float acc[4][8];
#pragma unroll
    for (int i = 0; i < 4; ++i)
#pragma unroll
        for (int c = 0; c < 8; ++c) acc[i][c] = 0.f;

    for (int kt = 0; kt < 4; ++kt) {
        // stage A (=L+E) and C (=L*E) for j in [kt*16, kt*16+16)
#pragma unroll
        for (int it = 0; it < 2; ++it) {
            int f  = t + 256 * it;          // 0..511 (128 rows x 4 float4)
            int rl = f >> 2, c4 = f & 3;
            int col = kt * 16 + c4 * 4;
            int row = rowbase + rl;
            float4 l4 = make_float4(0.f, 0.f, 0.f, 0.f);
            float4 e4 = l4;
            if (row < NNODE) {
                l4 = *(const float4*)&L[row * 64 + col];
                e4 = *(const float4*)&Ein[row * 64 + col];
            }
            float* ap = &Atile[rl * 17 + c4 * 4];
            float* cp = &Ctile[rl * 17 + c4 * 4];
            ap[0] = l4.x + e4.x; ap[1] = l4.y + e4.y; ap[2] = l4.z + e4.z; ap[3] = l4.w + e4.w;
            cp[0] = l4.x * e4.x; cp[1] = l4.y * e4.y; cp[2] = l4.z * e4.z; cp[3] = l4.w * e4.w;
        }
        __syncthreads();
#pragma unroll
        for (int j = 0; j < 16; ++j) {
            int jj = kt * 16 + j;
            float4 w1a = *(const float4*)&Wl[jj * 64 + ct * 8];
            float4 w1b = *(const float4*)&Wl[jj * 64 + ct * 8 + 4];
            float4 w2a = *(const float4*)&Wl[(64 + jj) * 64 + ct * 8];
            float4 w2b = *(const float4*)&Wl[(64 + jj) * 64 + ct * 8 + 4];
#pragma unroll
            for (int i = 0; i < 4; ++i) {
                float a = Atile[(rg * 4 + i) * 17 + j];
                float c = Ctile[(rg * 4 + i) * 17 + j];
                acc[i][0] += a * w1a.x + c * w2a.x;
                acc[i][1] += a * w1a.y + c * w2a.y;
                acc[i][2] += a * w1a.z + c * w2a.z;
                acc[i][3] += a * w1a.w + c * w2a.w;
                acc[i][4] += a * w1b.x + c * w2b.x;
                acc[i][5] += a * w1b.y + c * w2b.y;
                acc[i][6] += a * w1b.z + c * w2b.z;
                acc[i][7] += a * w1b.w + c * w2b.w;
            }
        }
        __syncthreads();
    }

#pragma unroll
    for (int i = 0; i < 4; ++i) {
        int row = rowbase + rg * 4 + i;
        if (row < NNODE) {
            float4 o0, o1;
            float v;
            v = acc[i][0] + bias[ct * 8 + 0]; o0.x = v >= 0.f ? v : 0.2f * v;
            v = acc[i][1] + bias[ct * 8 + 1]; o0.y = v >= 0.f ? v : 0.2f * v;
            v = acc[i][2] + bias[ct * 8 + 2]; o0.z = v >= 0.f ? v : 0.2f * v;
            v = acc[i][3] + bias[ct * 8 + 3]; o0.w = v >= 0.f ? v : 0.2f * v;
            v = acc[i][4] + bias[ct * 8 + 4]; o1.x = v >= 0.f ? v : 0.2f * v;
            v = acc[i][5] + bias[ct * 8 + 5]; o1.y = v >= 0.f ? v : 0.2f * v;
            v = acc[i][6] + bias[ct * 8 + 6]; o1.z = v >= 0.f ? v : 0.2f * v;
            v = acc[i][7] + bias[ct * 8 + 7]; o1.w = v >= 0.f ? v : 0.2f * v;
            *(float4*)&Eout[row * 64 + ct * 8]     = o0;
            *(float4*)&Eout[row * 64 + ct * 8 + 4] = o1;
        }
    }
}

// ---------------------------------------------------------------------------
// Gather: one wave per output row-segment; optional row L2-normalization.
// out layout: 3 groups x 1024 rows x 256 cols; segment seg covers cols seg*64..
// ---------------------------------------------------------------------------
__global__ __launch_bounds__(256) void k_gather(const float* __restrict__ E,
                                                const int* __restrict__ user_idx,
                                                const int* __restrict__ pos_idx,
                                                const int* __restrict__ neg_idx,
                                                float* __restrict__ out,
                                                int seg, int normalize) {
    int wid  = threadIdx.x >> 6;
    int lane = threadIdx.x & 63;
    int o = blockIdx.x * 4 + wid;          // 0 .. 3*BATCH-1
    if (o >= 3 * BATCH) return;
    int g = o >> 10, b = o & 1023;
    int row;
    if (g == 0)      row = user_idx[b];
    else if (g == 1) row = N_USERC + pos_idx[b];
    else             row = N_USERC + neg_idx[b];
    float v = E[row * DIM + lane];
    if (normalize) {
        float ss = v * v;
#pragma unroll
        for (int m = 32; m; m >>= 1) ss += __shfl_xor(ss, m, 64);
        float nrm = sqrtf(ss);
        nrm = fmaxf(nrm, 1e-12f);
        v = v / nrm;
    }
    out[(g * BATCH + b) * 256 + seg * 64 + lane] = v;
}

// ---------------------------------------------------------------------------
// launch
// ---------------------------------------------------------------------------
extern "C" void kernel_launch(void* const* d_in, const int* in_sizes, int n_in,
                              void* d_out, int out_size, void* d_ws, size_t ws_size,
                              hipStream_t stream) {
    const float* user_emb  = (const float*)d_in[0];
    const float* item_emb  = (const float*)d_in[1];
    const float* lin1_w    = (const float*)d_in[2];
    const float* lin1_b    = (const float*)d_in[3];
    const float* lin2_w    = (const float*)d_in[4];
    const float* lin2_b    = (const float*)d_in[5];
    const float* w1        = (const float*)d_in[6];
    const float* b1        = (const float*)d_in[7];
    const float* w2        = (const float*)d_in[8];
    const float* b2        = (const float*)d_in[9];
    const int*   lap_row   = (const int*)d_in[10];
    const int*   lap_col   = (const int*)d_in[11];
    const float* lap_val   = (const float*)d_in[12];
    const int*   user_idx  = (const int*)d_in[13];
    const float* user_feat = (const float*)d_in[14];
    const int*   pos_idx   = (const int*)d_in[15];
    const int*   neg_idx   = (const int*)d_in[16];
    const float* mlp_ratio = (const float*)d_in[17];
    float* out = (float*)d_out;

    // workspace carve-up
    char* p = (char*)d_ws;
    auto carve = [&](size_t bytes) { void* r = (void*)p; p += (bytes + 255) & ~(size_t)255; return r; };
    float* E      = (float*)carve((size_t)NNODE * DIM * 4);
    float* L      = (float*)carve((size_t)NNODE * DIM * 4);
    int*   rowptr = (int*)carve((size_t)(NNODE + 1) * 4);
    int*   cursor = (int*)carve((size_t)NNODE * 4);     // doubles as counts
    int*   colss  = (int*)carve((size_t)NNZC * 4);
    float* valss  = (float*)carve((size_t)NNZC * 4);
    int*   winner = (int*)carve((size_t)N_USERC * 4);
    int*   bsums  = (int*)carve(256 * 4);

    const int nS = (NNODE + 1023) / 1024;               // 147

    // --- CSR build ---
    hipMemsetAsync(cursor, 0, (size_t)NNODE * 4, stream);
    hipMemsetAsync(winner, 0xFF, (size_t)N_USERC * 4, stream);
    k_hist<<<(NNZC + 255) / 256, 256, 0, stream>>>(lap_row, cursor);
    k_s1<<<nS, 1024, 0, stream>>>(cursor, bsums);
    k_s2<<<1, 256, 0, stream>>>(bsums, nS);
    k_s3<<<nS, 1024, 0, stream>>>(cursor, bsums, rowptr, cursor);
    k_scatter<<<(NNZC + 255) / 256, 256, 0, stream>>>(lap_row, lap_col, lap_val,
                                                      cursor, colss, valss);

    // --- E0 ---
    k_copy_E<<<(NNODE * DIM / 4 + 255) / 256, 256, 0, stream>>>(user_emb, item_emb, E);
    k_winner<<<(BATCH + 255) / 256, 256, 0, stream>>>(user_idx, winner);
    k_mlp_update<<<BATCH, 64, 0, stream>>>(user_emb, user_feat, lin1_w, lin1_b,
                                           lin2_w, lin2_b, mlp_ratio, user_idx, winner, E);
    k_gather<<<(3 * BATCH) / 4, 256, 0, stream>>>(E, user_idx, pos_idx, neg_idx, out, 0, 0);

    // --- layers ---
    for (int k = 0; k < NLAYERS; ++k) {
        k_spmm<<<(NNODE + 3) / 4, 256, 0, stream>>>(rowptr, colss, valss, E, L);
        k_transform<<<(NNODE + 127) / 128, 256, 0, stream>>>(
            L, E, w1 + (size_t)k * DIM * DIM, b1 + (size_t)k * DIM,
            w2 + (size_t)k * DIM * DIM, b2 + (size_t)k * DIM, E);
        k_gather<<<(3 * BATCH) / 4, 256, 0, stream>>>(E, user_idx, pos_idx, neg_idx,
                                                      out, k + 1, 1);
    }
}

// Round 2
// 1019.341 us; speedup vs baseline: 1.0208x; 1.0208x over previous
//
#include <hip/hip_runtime.h>
#include <hip/hip_bf16.h>

#define N_USERC 50000
#define N_ITEMC 100000
#define NNODE   150000
#define DIM     64
#define NLAYERS 3
#define NNZC    2400000
#define BATCH   1024
#define NBUCK   1024
#define RPB     147     // rows per bucket; 1024*147 = 150528 >= 150000

// ---------------------------------------------------------------------------
// helpers
// ---------------------------------------------------------------------------
__device__ __forceinline__ float bf2f(ushort u) {
    return __uint_as_float(((unsigned)u) << 16);
}
__device__ __forceinline__ ushort f2bf(float f) {
    unsigned u = __float_as_uint(f);
    u += 0x7FFF + ((u >> 16) & 1);          // RNE
    return (ushort)(u >> 16);
}

__device__ __forceinline__ int block_excl_scan(int v, int* lds) {
    int lane = threadIdx.x & 63;
    int wid  = threadIdx.x >> 6;
    int nw   = (blockDim.x + 63) >> 6;
    int inc = v;
#pragma unroll
    for (int o = 1; o < 64; o <<= 1) {
        int n = __shfl_up(inc, o, 64);
        if (lane >= o) inc += n;
    }
    if (lane == 63) lds[wid] = inc;
    __syncthreads();
    if (wid == 0) {
        int tv = (lane < nw) ? lds[lane] : 0;
#pragma unroll
        for (int o = 1; o < 16; o <<= 1) {
            int n = __shfl_up(tv, o, 64);
            if (lane >= o) tv += n;
        }
        if (lane < nw) lds[lane] = tv;
    }
    __syncthreads();
    int woff = (wid == 0) ? 0 : lds[wid - 1];
    return woff + (inc - v);
}

// ---------------------------------------------------------------------------
// E construction (f32 optional + bf16 mirror)
// ---------------------------------------------------------------------------
__global__ void k_copy_E(const float* __restrict__ ue, const float* __restrict__ ie,
                         float* __restrict__ E, ushort* __restrict__ Ebf) {
    int i = blockIdx.x * blockDim.x + threadIdx.x;        // float4 index
    const int userEnd = N_USERC * DIM / 4;
    const int total   = NNODE * DIM / 4;
    if (i < total) {
        float4 v;
        if (i < userEnd) v = ((const float4*)ue)[i];
        else             v = ((const float4*)ie)[i - userEnd];
        if (E) ((float4*)E)[i] = v;
        ushort4 b;
        b.x = f2bf(v.x); b.y = f2bf(v.y); b.z = f2bf(v.z); b.w = f2bf(v.w);
        ((ushort4*)Ebf)[i] = b;
    }
}

__global__ void k_winner(const int* __restrict__ user_idx, int* __restrict__ winner) {
    int b = blockIdx.x * blockDim.x + threadIdx.x;
    if (b < BATCH) atomicMax(&winner[user_idx[b]], b);
}

__global__ void k_mlp_update(const float* __restrict__ user_emb,
                             const float* __restrict__ user_feat,
                             const float* __restrict__ l1w, const float* __restrict__ l1b,
                             const float* __restrict__ l2w, const float* __restrict__ l2b,
                             const float* __restrict__ ratio_p,
                             const int* __restrict__ user_idx,
                             const int* __restrict__ winner,
                             float* __restrict__ E, ushort* __restrict__ Ebf) {
    int b = blockIdx.x;        // grid = BATCH, block = 64
    int d = threadIdx.x;
    int u = user_idx[b];
    if (winner[u] != b) return;                  // last-occurrence-wins
    float ratio = ratio_p[0];
    float uf0 = user_feat[b * 4 + 0], uf1 = user_feat[b * 4 + 1];
    float uf2 = user_feat[b * 4 + 2], uf3 = user_feat[b * 4 + 3];
    float acc = l2b[d];
#pragma unroll
    for (int j = 0; j < 32; ++j) {
        float h = l1b[j] + uf0 * l1w[0 * 32 + j] + uf1 * l1w[1 * 32 + j]
                         + uf2 * l1w[2 * 32 + j] + uf3 * l1w[3 * 32 + j];
        acc += h * l2w[j * DIM + d];
    }
    float v = user_emb[u * DIM + d] * (1.f - ratio) + acc * ratio;
    if (E) E[u * DIM + d] = v;
    Ebf[u * DIM + d] = f2bf(v);
}

// ---------------------------------------------------------------------------
// CSR build: hist -> scan -> two-phase binned scatter (packed uint64)
// packed = [ zeros:6 | rowoff:8 (bits 50..57) | col:18 (bits 32..49) | val:32 ]
// ---------------------------------------------------------------------------
__global__ void k_hist(const int* __restrict__ rows, int* __restrict__ counts) {
    int i = blockIdx.x * blockDim.x + threadIdx.x;
    if (i < NNZC) atomicAdd(&counts[rows[i]], 1);
}

__global__ void k_s1(const int* __restrict__ counts, int* __restrict__ bsums) {
    __shared__ int lds[16];
    int i = blockIdx.x * 1024 + threadIdx.x;
    int v = (i < NNODE) ? counts[i] : 0;
#pragma unroll
    for (int m = 32; m; m >>= 1) v += __shfl_xor(v, m, 64);
    if ((threadIdx.x & 63) == 0) lds[threadIdx.x >> 6] = v;
    __syncthreads();
    if (threadIdx.x == 0) {
        int s = 0;
#pragma unroll
        for (int w = 0; w < 16; ++w) s += lds[w];
        bsums[blockIdx.x] = s;
    }
}

__global__ void k_s2(int* __restrict__ bsums, int nblocks) {
    __shared__ int lds[16];
    int t = threadIdx.x;                    // block 256
    int v = (t < nblocks) ? bsums[t] : 0;
    int excl = block_excl_scan(v, lds);
    if (t < nblocks) bsums[t] = excl;
}

__global__ void k_s3(const int* __restrict__ counts, const int* __restrict__ bsums,
                     int* __restrict__ rowptr, int* __restrict__ cursor) {
    __shared__ int lds[16];
    int i = blockIdx.x * 1024 + threadIdx.x;
    int v = (i < NNODE) ? counts[i] : 0;
    int excl = block_excl_scan(v, lds);
    int pref = bsums[blockIdx.x] + excl;
    if (i < NNODE) {
        rowptr[i] = pref;
        cursor[i] = pref;
    } else if (i == NNODE) {
        rowptr[NNODE] = pref;               // == NNZ
    }
}

__global__ void k_initbcur(const int* __restrict__ rowptr, int* __restrict__ bcur) {
    int b = blockIdx.x * blockDim.x + threadIdx.x;
    if (b < NBUCK) {
        int r0 = b * RPB; if (r0 > NNODE) r0 = NNODE;
        bcur[b * 16] = rowptr[r0];          // 64B-strided cursors (no line sharing)
    }
}

__global__ void k_binscatter(const int* __restrict__ rows, const int* __restrict__ cols,
                             const float* __restrict__ vals, int* __restrict__ bcur,
                             unsigned long long* __restrict__ tmp) {
    int i = blockIdx.x * blockDim.x + threadIdx.x;
    if (i < NNZC) {
        int r = rows[i], c = cols[i];
        float v = vals[i];
        int b = r / RPB;
        int ro = r - b * RPB;
        unsigned hi = ((unsigned)ro << 18) | (unsigned)c;
        unsigned long long pk = ((unsigned long long)hi << 32) | __float_as_uint(v);
        int pos = atomicAdd(&bcur[b * 16], 1);
        tmp[pos] = pk;
    }
}

__global__ __launch_bounds__(256) void k_finalize(const int* __restrict__ rowptr,
                                                  const unsigned long long* __restrict__ tmp,
                                                  int* __restrict__ cursor,
                                                  unsigned long long* __restrict__ csr) {
    int b = blockIdx.x;                      // grid = NBUCK
    int r0 = b * RPB; if (r0 > NNODE) r0 = NNODE;
    int r1 = r0 + RPB; if (r1 > NNODE) r1 = NNODE;
    int s = rowptr[r0], e = rowptr[r1];
    for (int p = s + (int)threadIdx.x; p < e; p += 256) {
        unsigned long long pk = tmp[p];
        int ro = (int)(pk >> 50);
        int row = r0 + ro;
        int q = atomicAdd(&cursor[row], 1);
        csr[q] = pk;                         // ro bits kept; spmm masks col
    }
}

// ---------------------------------------------------------------------------
// SpMM: one wave per row, lane = dim. bf16 E gather (128B/row), unroll 4.
// ---------------------------------------------------------------------------
__global__ __launch_bounds__(256) void k_spmm(const int* __restrict__ rowptr,
                                              const unsigned long long* __restrict__ csr,
                                              const ushort* __restrict__ Ebf,
                                              float* __restrict__ L) {
    int wid  = threadIdx.x >> 6;
    int lane = threadIdx.x & 63;
    int row  = blockIdx.x * 4 + wid;
    if (row >= NNODE) return;
    int s = rowptr[row], e = rowptr[row + 1];
    float acc = 0.f;
    for (int base = s; base < e; base += 64) {
        int n = e - base; if (n > 64) n = 64;
        unsigned long long pk = 0;
        if (base + lane < e) pk = csr[base + lane];
        int i = 0;
        for (; i + 4 <= n; i += 4) {
            unsigned long long p0 = __shfl(pk, i, 64);
            unsigned long long p1 = __shfl(pk, i + 1, 64);
            unsigned long long p2 = __shfl(pk, i + 2, 64);
            unsigned long long p3 = __shfl(pk, i + 3, 64);
            int c0 = ((int)(p0 >> 32)) & 0x3FFFF;
            int c1 = ((int)(p1 >> 32)) & 0x3FFFF;
            int c2 = ((int)(p2 >> 32)) & 0x3FFFF;
            int c3 = ((int)(p3 >> 32)) & 0x3FFFF;
            float e0 = bf2f(Ebf[c0 * DIM + lane]);
            float e1 = bf2f(Ebf[c1 * DIM + lane]);
            float e2 = bf2f(Ebf[c2 * DIM + lane]);
            float e3 = bf2f(Ebf[c3 * DIM + lane]);
            acc += __uint_as_float((unsigned)p0) * e0;
            acc += __uint_as_float((unsigned)p1) * e1;
            acc += __uint_as_float((unsigned)p2) * e2;
            acc += __uint_as_float((unsigned)p3) * e3;
        }
        for (; i < n; ++i) {
            unsigned long long p = __shfl(pk, i, 64);
            int c = ((int)(p >> 32)) & 0x3FFFF;
            acc += __uint_as_float((unsigned)p) * bf2f(Ebf[c * DIM + lane]);
        }
    }
    L[row * DIM + lane] = acc;
}

// ---------------------------------------------------------------------------
// Transform: E_new = leaky_relu([L+E, L*E] @ [W1;W2] + b1 + b2), in place.
// Ein f32 if non-null else bf16 mirror. Always refreshes bf16 mirror.
// ---------------------------------------------------------------------------
__global__ __launch_bounds__(256) void k_transform(const float* __restrict__ L,
                                                   const float* __restrict__ Ein,
                                                   const ushort* __restrict__ Ebf_in,
                                                   const float* __restrict__ w1k,
                                                   const float* __restrict__ b1k,
                                                   const float* __restrict__ w2k,
                                                   const float* __restrict__ b2k,
                                                   float* __restrict__ Eout,
                                                   ushort* __restrict__ Ebf_out) {
    __shared__ float Wl[128 * 64];          // rows 0..63 = W1, 64..127 = W2
    __shared__ float bias[64];
    __shared__ float Atile[128 * 17];
    __shared__ float Ctile[128 * 17];

    int t = threadIdx.x;
    for (int idx = t; idx < 1024; idx += 256) {
        ((float4*)Wl)[idx]          = ((const float4*)w1k)[idx];
        ((float4*)(Wl + 4096))[idx] = ((const float4*)w2k)[idx];
    }
    if (t < 64) bias[t] = b1k[t] + b2k[t];

    const int rowbase = blockIdx.x * 128;
    const int ct = t & 7;       // cols ct*8 .. ct*8+7
    const int rg = t >> 3;      // rows rg*4 .. rg*4+3

    float acc[4][8];
#pragma unroll
    for (int i = 0; i < 4; ++i)
#pragma unroll
        for (int c = 0; c < 8; ++c) acc[i][c] = 0.f;

    for (int kt = 0; kt < 4; ++kt) {
#pragma unroll
        for (int it = 0; it < 2; ++it) {
            int f  = t + 256 * it;          // 0..511 (128 rows x 4 float4)
            int rl = f >> 2, c4 = f & 3;
            int col = kt * 16 + c4 * 4;
            int row = rowbase + rl;
            float4 l4 = make_float4(0.f, 0.f, 0.f, 0.f);
            float4 e4 = l4;
            if (row < NNODE) {
                l4 = *(const float4*)&L[row * 64 + col];
                if (Ein) {
                    e4 = *(const float4*)&Ein[row * 64 + col];
                } else {
                    ushort4 ub = *(const ushort4*)&Ebf_in[row * 64 + col];
                    e4 = make_float4(bf2f(ub.x), bf2f(ub.y), bf2f(ub.z), bf2f(ub.w));
                }
            }
            float* ap = &Atile[rl * 17 + c4 * 4];
            float* cp = &Ctile[rl * 17 + c4 * 4];
            ap[0] = l4.x + e4.x; ap[1] = l4.y + e4.y; ap[2] = l4.z + e4.z; ap[3] = l4.w + e4.w;
            cp[0] = l4.x * e4.x; cp[1] = l4.y * e4.y; cp[2] = l4.z * e4.z; cp[3] = l4.w * e4.w;
        }
        __syncthreads();
#pragma unroll
        for (int j = 0; j < 16; ++j) {
            int jj = kt * 16 + j;
            float4 w1a = *(const float4*)&Wl[jj * 64 + ct * 8];
            float4 w1b = *(const float4*)&Wl[jj * 64 + ct * 8 + 4];
            float4 w2a = *(const float4*)&Wl[(64 + jj) * 64 + ct * 8];
            float4 w2b = *(const float4*)&Wl[(64 + jj) * 64 + ct * 8 + 4];
#pragma unroll
            for (int i = 0; i < 4; ++i) {
                float a = Atile[(rg * 4 + i) * 17 + j];
                float c = Ctile[(rg * 4 + i) * 17 + j];
                acc[i][0] += a * w1a.x + c * w2a.x;
                acc[i][1] += a * w1a.y + c * w2a.y;
                acc[i][2] += a * w1a.z + c * w2a.z;
                acc[i][3] += a * w1a.w + c * w2a.w;
                acc[i][4] += a * w1b.x + c * w2b.x;
                acc[i][5] += a * w1b.y + c * w2b.y;
                acc[i][6] += a * w1b.z + c * w2b.z;
                acc[i][7] += a * w1b.w + c * w2b.w;
            }
        }
        __syncthreads();
    }

#pragma unroll
    for (int i = 0; i < 4; ++i) {
        int row = rowbase + rg * 4 + i;
        if (row < NNODE) {
            float o[8];
#pragma unroll
            for (int c = 0; c < 8; ++c) {
                float v = acc[i][c] + bias[ct * 8 + c];
                o[c] = v >= 0.f ? v : 0.2f * v;
            }
            if (Eout) {
                *(float4*)&Eout[row * 64 + ct * 8]     = make_float4(o[0], o[1], o[2], o[3]);
                *(float4*)&Eout[row * 64 + ct * 8 + 4] = make_float4(o[4], o[5], o[6], o[7]);
            }
            uint4 pb;
            pb.x = (unsigned)f2bf(o[0]) | ((unsigned)f2bf(o[1]) << 16);
            pb.y = (unsigned)f2bf(o[2]) | ((unsigned)f2bf(o[3]) << 16);
            pb.z = (unsigned)f2bf(o[4]) | ((unsigned)f2bf(o[5]) << 16);
            pb.w = (unsigned)f2bf(o[6]) | ((unsigned)f2bf(o[7]) << 16);
            *(uint4*)&Ebf_out[row * 64 + ct * 8] = pb;
        }
    }
}

// ---------------------------------------------------------------------------
// Gather: one wave per output row-segment; optional row L2-normalization.
// ---------------------------------------------------------------------------
__global__ __launch_bounds__(256) void k_gather(const float* __restrict__ Ein,
                                                const ushort* __restrict__ Ebf,
                                                const int* __restrict__ user_idx,
                                                const int* __restrict__ pos_idx,
                                                const int* __restrict__ neg_idx,
                                                float* __restrict__ out,
                                                int seg, int normalize) {
    int wid  = threadIdx.x >> 6;
    int lane = threadIdx.x & 63;
    int o = blockIdx.x * 4 + wid;          // 0 .. 3*BATCH-1
    if (o >= 3 * BATCH) return;
    int g = o >> 10, b = o & 1023;
    int row;
    if (g == 0)      row = user_idx[b];
    else if (g == 1) row = N_USERC + pos_idx[b];
    else             row = N_USERC + neg_idx[b];
    float v = Ein ? Ein[row * DIM + lane] : bf2f(Ebf[row * DIM + lane]);
    if (normalize) {
        float ss = v * v;
#pragma unroll
        for (int m = 32; m; m >>= 1) ss += __shfl_xor(ss, m, 64);
        float nrm = sqrtf(ss);
        nrm = fmaxf(nrm, 1e-12f);
        v = v / nrm;
    }
    out[(g * BATCH + b) * 256 + seg * 64 + lane] = v;
}

// ---------------------------------------------------------------------------
// launch
// ---------------------------------------------------------------------------
extern "C" void kernel_launch(void* const* d_in, const int* in_sizes, int n_in,
                              void* d_out, int out_size, void* d_ws, size_t ws_size,
                              hipStream_t stream) {
    const float* user_emb  = (const float*)d_in[0];
    const float* item_emb  = (const float*)d_in[1];
    const float* lin1_w    = (const float*)d_in[2];
    const float* lin1_b    = (const float*)d_in[3];
    const float* lin2_w    = (const float*)d_in[4];
    const float* lin2_b    = (const float*)d_in[5];
    const float* w1        = (const float*)d_in[6];
    const float* b1        = (const float*)d_in[7];
    const float* w2        = (const float*)d_in[8];
    const float* b2        = (const float*)d_in[9];
    const int*   lap_row   = (const int*)d_in[10];
    const int*   lap_col   = (const int*)d_in[11];
    const float* lap_val   = (const float*)d_in[12];
    const int*   user_idx  = (const int*)d_in[13];
    const float* user_feat = (const float*)d_in[14];
    const int*   pos_idx   = (const int*)d_in[15];
    const int*   neg_idx   = (const int*)d_in[16];
    const float* mlp_ratio = (const float*)d_in[17];
    float* out = (float*)d_out;

    // workspace carve-up (offsets; E f32 only if ws_size allows)
    size_t off = 0;
    auto carve = [&](size_t bytes) { size_t r = off; off = (off + bytes + 255) & ~(size_t)255; return r; };
    size_t oL      = carve((size_t)NNODE * DIM * 4);      // also aliases tmp (19.2MB <= 38.4MB)
    size_t oEbf    = carve((size_t)NNODE * DIM * 2);
    size_t oRowptr = carve((size_t)(NNODE + 1) * 4);
    size_t oCursor = carve((size_t)NNODE * 4);            // doubles as counts
    size_t oCsr    = carve((size_t)NNZC * 8);
    size_t oWinner = carve((size_t)N_USERC * 4);
    size_t oBsums  = carve(256 * 4);
    size_t oBcur   = carve((size_t)NBUCK * 16 * 4);
    size_t oE      = carve((size_t)NNODE * DIM * 4);
    bool dual = (ws_size >= off);                          // f32 E fits?

    char* base = (char*)d_ws;
    float*              L      = (float*)(base + oL);
    unsigned long long* tmp    = (unsigned long long*)(base + oL);   // alias: dead before first spmm
    ushort*             Ebf    = (ushort*)(base + oEbf);
    int*                rowptr = (int*)(base + oRowptr);
    int*                cursor = (int*)(base + oCursor);
    unsigned long long* csr    = (unsigned long long*)(base + oCsr);
    int*                winner = (int*)(base + oWinner);
    int*                bsums  = (int*)(base + oBsums);
    int*                bcur   = (int*)(base + oBcur);
    float*              E      = dual ? (float*)(base + oE) : nullptr;

    const int nS = (NNODE + 1023) / 1024;               // 147

    // --- CSR build ---
    hipMemsetAsync(cursor, 0, (size_t)NNODE * 4, stream);
    hipMemsetAsync(winner, 0xFF, (size_t)N_USERC * 4, stream);
    k_hist<<<(NNZC + 255) / 256, 256, 0, stream>>>(lap_row, cursor);
    k_s1<<<nS, 1024, 0, stream>>>(cursor, bsums);
    k_s2<<<1, 256, 0, stream>>>(bsums, nS);
    k_s3<<<nS, 1024, 0, stream>>>(cursor, bsums, rowptr, cursor);
    k_initbcur<<<(NBUCK + 255) / 256, 256, 0, stream>>>(rowptr, bcur);
    k_binscatter<<<(NNZC + 255) / 256, 256, 0, stream>>>(lap_row, lap_col, lap_val, bcur, tmp);
    k_finalize<<<NBUCK, 256, 0, stream>>>(rowptr, tmp, cursor, csr);

    // --- E0 ---
    k_copy_E<<<(NNODE * DIM / 4 + 255) / 256, 256, 0, stream>>>(user_emb, item_emb, E, Ebf);
    k_winner<<<(BATCH + 255) / 256, 256, 0, stream>>>(user_idx, winner);
    k_mlp_update<<<BATCH, 64, 0, stream>>>(user_emb, user_feat, lin1_w, lin1_b,
                                           lin2_w, lin2_b, mlp_ratio, user_idx, winner, E, Ebf);
    k_gather<<<(3 * BATCH) / 4, 256, 0, stream>>>(E, Ebf, user_idx, pos_idx, neg_idx, out, 0, 0);

    // --- layers ---
    for (int k = 0; k < NLAYERS; ++k) {
        k_spmm<<<(NNODE + 3) / 4, 256, 0, stream>>>(rowptr, csr, Ebf, L);
        k_transform<<<(NNODE + 127) / 128, 256, 0, stream>>>(
            L, E, Ebf, w1 + (size_t)k * DIM * DIM, b1 + (size_t)k * DIM,
            w2 + (size_t)k * DIM * DIM, b2 + (size_t)k * DIM, E, Ebf);
        k_gather<<<(3 * BATCH) / 4, 256, 0, stream>>>(E, Ebf, user_idx, pos_idx, neg_idx,
                                                      out, k + 1, 1);
    }
}